// Round 3
// baseline (112.504 us; speedup 1.0000x reference)
//
#include <hip/hip_runtime.h>
#include <hip/hip_cooperative_groups.h>

namespace cg = cooperative_groups;

// Sinkhorn top-K collapsed to a per-row 1-D Newton solve — single cooperative kernel.
// B=512 rows, N=4096 cols, K=256, eps=0.1.
// t[n] = exp((1-2*s[n]) * alpha), alpha = 1/(M*eps), M = global max of (s-anchor)^2.
// Solve h(rho) = sum_n rho*t/(rho*t+1) = K (concave, monotone; Newton from below,
// rho0 = K/sum(t) => h(rho0) < K). Then P1 = mu*w, P0 = mu*(1-w), w = 1/(rho*t+1).
// Reference's 200 Sinkhorn sweeps are machine-converged (Birkhoff contraction
// ~0.876^400), so the fixed point equals the reference output (absmax 9.5e-7 R1/R2).
// R3: fused into ONE cooperative kernel (was 2 nodes): block b owns row b, row max
// -> ws[b], grid.sync(), global max from 512 row-maxes (L2-hot), row still in regs.

#define NROWS 512
#define NCOLS 4096
#define KSEL 256
#define EPSREG 0.1f
#define NEWTON_ITERS 8   // converged by ~6 (absmax identical at 12 and 32 iters)

__device__ __forceinline__ float fastrcp(float x) {
#if __has_builtin(__builtin_amdgcn_rcpf)
    return __builtin_amdgcn_rcpf(x);
#else
    return 1.0f / x;
#endif
}

__global__ __launch_bounds__(256) void sinkhorn_fused(const float* __restrict__ s,
                                                      float* __restrict__ rowmax,
                                                      float* __restrict__ out) {
    const int b   = blockIdx.x;
    const int tid = threadIdx.x;
    const int wv  = tid >> 6;
    const int ln  = tid & 63;

    __shared__ float ldsm[4];
    __shared__ float ldss[4];
    __shared__ float lds[2][8];   // Newton ping-pong [phase][wave*2 + {A,Q}]

    // ---- phase 1: load own row, per-row cost max ----
    const float4* srow = (const float4*)(s + (size_t)b * NCOLS);
    float4 v[4];
#pragma unroll
    for (int j = 0; j < 4; ++j) v[j] = srow[tid + 256 * j];

    float m = 0.f;
#pragma unroll
    for (int j = 0; j < 4; ++j) {
        float xs[4] = {v[j].x, v[j].y, v[j].z, v[j].w};
#pragma unroll
        for (int e = 0; e < 4; ++e) {
            float x = xs[e];
            m = fmaxf(m, fmaxf(x * x, (x - 1.f) * (x - 1.f)));
        }
    }
#pragma unroll
    for (int off = 32; off >= 1; off >>= 1)
        m = fmaxf(m, __shfl_xor(m, off, 64));
    if (ln == 0) ldsm[wv] = m;
    __syncthreads();
    if (tid == 0)
        rowmax[b] = fmaxf(fmaxf(ldsm[0], ldsm[1]), fmaxf(ldsm[2], ldsm[3]));

    // ---- grid-wide barrier (device-scope fence included) ----
    cg::this_grid().sync();

    // ---- phase 2: global max from 512 row maxes (2 KB, L2-hot) ----
    m = fmaxf(rowmax[tid], rowmax[tid + 256]);
#pragma unroll
    for (int off = 32; off >= 1; off >>= 1)
        m = fmaxf(m, __shfl_xor(m, off, 64));
    if (ln == 0) ldsm[wv] = m;
    __syncthreads();
    const float M     = fmaxf(fmaxf(ldsm[0], ldsm[1]), fmaxf(ldsm[2], ldsm[3]));
    const float alpha = 1.0f / (M * EPSREG);
    const float c2    = -2.0f * alpha;

    // ---- t from registers + sum(t) ----
    float t[16];
    float sumt = 0.f;
#pragma unroll
    for (int j = 0; j < 4; ++j) {
        float xs[4] = {v[j].x, v[j].y, v[j].z, v[j].w};
#pragma unroll
        for (int e = 0; e < 4; ++e) {
            float tt = __expf(fmaf(xs[e], c2, alpha));   // exp((1-2x)*alpha)
            t[4 * j + e] = tt;
            sumt += tt;
        }
    }
#pragma unroll
    for (int off = 32; off >= 1; off >>= 1)
        sumt += __shfl_xor(sumt, off, 64);
    if (ln == 0) ldss[wv] = sumt;
    __syncthreads();
    sumt = ldss[0] + ldss[1] + ldss[2] + ldss[3];

    // rho0 = K/sum(t): h(rho0) < K strictly -> monotone Newton from below
    float rho = (float)KSEL / sumt;

#pragma unroll 1
    for (int it = 0; it < NEWTON_ITERS; ++it) {
        float a = 0.f, q = 0.f;
#pragma unroll
        for (int e = 0; e < 16; ++e) {
            float w = fastrcp(fmaf(rho, t[e], 1.0f));
            a += w;
            q = fmaf(w, w, q);
        }
#pragma unroll
        for (int off = 32; off >= 1; off >>= 1) {
            a += __shfl_xor(a, off, 64);
            q += __shfl_xor(q, off, 64);
        }
        const int ph = it & 1;
        if (ln == 0) { lds[ph][wv * 2] = a; lds[ph][wv * 2 + 1] = q; }
        __syncthreads();          // one barrier/iter; ping-pong handles WAR
        a = lds[ph][0] + lds[ph][2] + lds[ph][4] + lds[ph][6];
        q = lds[ph][1] + lds[ph][3] + lds[ph][5] + lds[ph][7];
        // h(rho) = N - A, h'(rho) = (A - Q)/rho
        rho += ((float)(KSEL - NCOLS) + a) * rho / (a - q);
    }

    // ---- write P: out[b,0,n] = mu*(1-w), out[b,1,n] = mu*w ----
    const float MU = 1.0f / (float)NCOLS;
    float4* o0 = (float4*)(out + (size_t)b * 2 * NCOLS);
    float4* o1 = (float4*)(out + (size_t)b * 2 * NCOLS + NCOLS);
#pragma unroll
    for (int j = 0; j < 4; ++j) {
        float r0[4], r1[4];
#pragma unroll
        for (int e = 0; e < 4; ++e) {
            float w  = fastrcp(fmaf(rho, t[4 * j + e], 1.0f));
            float p1 = MU * w;
            r1[e] = p1;
            r0[e] = MU - p1;
        }
        o0[tid + 256 * j] = make_float4(r0[0], r0[1], r0[2], r0[3]);
        o1[tid + 256 * j] = make_float4(r1[0], r1[1], r1[2], r1[3]);
    }
}

extern "C" void kernel_launch(void* const* d_in, const int* in_sizes, int n_in,
                              void* d_out, int out_size, void* d_ws, size_t ws_size,
                              hipStream_t stream) {
    const float* scores = (const float*)d_in[0];
    float* out = (float*)d_out;
    float* rowmax = (float*)d_ws;   // 512 floats; every slot written before read

    void* args[] = {(void*)&scores, (void*)&rowmax, (void*)&out};
    hipLaunchCooperativeKernel((const void*)sinkhorn_fused, dim3(NROWS), dim3(256),
                               args, 0, stream);
}

// Round 4
// 78.691 us; speedup vs baseline: 1.4297x; 1.4297x over previous
//
#include <hip/hip_runtime.h>

// Sinkhorn top-K collapsed to a per-row 1-D Newton solve. B=512, N=4096, K=256, eps=0.1.
// t[n] = exp((1-2*s[n]) * alpha), alpha = 1/(M*eps), M = global max of (s-anchor)^2.
// Solve h(rho) = sum_n rho*t/(rho*t+1) = K (concave, monotone; Newton from below,
// rho0 = K/sum(t)). P1 = mu*w, P0 = mu*(1-w), w = 1/(rho*t+1). Fixed point == the
// reference's machine-converged 200 Sinkhorn sweeps (absmax 9.5e-7, R1-R3).
//
// R4: cooperative grid.sync REVERTED (measured ~30 us of the R3 kernel's 43 us —
// kernel boundary is a cheaper device barrier). Back to 2 kernels, but the solve
// kernel now uses 1024 thr/block (16 waves) -> 2 blocks/CU = 32 waves/CU = 100%
// occupancy (was 25% in R2), hiding load latency, store drain, and barrier waits.
// Newton 8 -> 6 iters (absmax bit-identical at 8/12/32).

#define NROWS 512
#define NCOLS 4096
#define KSEL 256
#define EPSREG 0.1f
#define NEWTON_ITERS 6
#define KMAX_BLOCKS 1024

__device__ __forceinline__ float fastrcp(float x) {
#if __has_builtin(__builtin_amdgcn_rcpf)
    return __builtin_amdgcn_rcpf(x);
#else
    return 1.0f / x;
#endif
}

// ---- K1: per-block max of max(s^2,(s-1)^2); 1024 blocks x 256 thr ----
__global__ __launch_bounds__(256) void kmax_kernel(const float4* __restrict__ s4,
                                                   float* __restrict__ blkmax) {
    const int tid = blockIdx.x * 256 + threadIdx.x;   // 262144 threads
    float m = 0.f;
#pragma unroll
    for (int j = 0; j < 2; ++j) {                     // 262144*2 = 524288 float4
        float4 v = s4[tid + 262144 * j];
        m = fmaxf(m, fmaxf(v.x * v.x, (v.x - 1.f) * (v.x - 1.f)));
        m = fmaxf(m, fmaxf(v.y * v.y, (v.y - 1.f) * (v.y - 1.f)));
        m = fmaxf(m, fmaxf(v.z * v.z, (v.z - 1.f) * (v.z - 1.f)));
        m = fmaxf(m, fmaxf(v.w * v.w, (v.w - 1.f) * (v.w - 1.f)));
    }
#pragma unroll
    for (int off = 32; off >= 1; off >>= 1)
        m = fmaxf(m, __shfl_xor(m, off, 64));
    __shared__ float wmax[4];
    if ((threadIdx.x & 63) == 0) wmax[threadIdx.x >> 6] = m;
    __syncthreads();
    if (threadIdx.x == 0)
        blkmax[blockIdx.x] = fmaxf(fmaxf(wmax[0], wmax[1]), fmaxf(wmax[2], wmax[3]));
}

// ---- K2: per-row Newton solve + write P; 512 blocks x 1024 thr (16 waves) ----
__global__ __launch_bounds__(1024) void sinkhorn_kernel(const float* __restrict__ s,
                                                        const float* __restrict__ blkmax,
                                                        float* __restrict__ out) {
    const int b   = blockIdx.x;
    const int tid = threadIdx.x;
    const int wv  = tid >> 6;          // wave 0..15
    const int ln  = tid & 63;

    __shared__ __align__(16) float ldsm[16];
    __shared__ __align__(16) float ldss[16];
    __shared__ __align__(16) float lds[2][32];   // Newton ping-pong: 16 x {A,Q}

    // ---- row load (1 float4/thread), issued before anything depends on it
    const float4* srow = (const float4*)(s + (size_t)b * NCOLS);
    const float4 v = srow[tid];

    // ---- global max from 1024 block maxes (coalesced, L2/L3-hot)
    float m = blkmax[tid];
#pragma unroll
    for (int off = 32; off >= 1; off >>= 1)
        m = fmaxf(m, __shfl_xor(m, off, 64));
    if (ln == 0) ldsm[wv] = m;
    __syncthreads();                   // barrier 1
    {
        const float4* p = (const float4*)ldsm;   // same-addr broadcast reads: free
        float4 a0 = p[0], a1 = p[1], a2 = p[2], a3 = p[3];
        m = fmaxf(fmaxf(fmaxf(a0.x, a0.y), fmaxf(a0.z, a0.w)),
                  fmaxf(fmaxf(a1.x, a1.y), fmaxf(a1.z, a1.w)));
        m = fmaxf(m, fmaxf(fmaxf(fmaxf(a2.x, a2.y), fmaxf(a2.z, a2.w)),
                           fmaxf(fmaxf(a3.x, a3.y), fmaxf(a3.z, a3.w))));
    }
    const float alpha = 1.0f / (m * EPSREG);
    const float c2    = -2.0f * alpha;

    // ---- t = exp((1-2x)*alpha), 4 per thread, + sum(t)
    float t[4];
    const float xs[4] = {v.x, v.y, v.z, v.w};
    float sumt = 0.f;
#pragma unroll
    for (int e = 0; e < 4; ++e) {
        float tt = __expf(fmaf(xs[e], c2, alpha));
        t[e] = tt;
        sumt += tt;
    }
#pragma unroll
    for (int off = 32; off >= 1; off >>= 1)
        sumt += __shfl_xor(sumt, off, 64);
    if (ln == 0) ldss[wv] = sumt;
    __syncthreads();                   // barrier 2
    {
        const float4* p = (const float4*)ldss;
        float4 a0 = p[0], a1 = p[1], a2 = p[2], a3 = p[3];
        sumt = (a0.x + a0.y + a0.z + a0.w) + (a1.x + a1.y + a1.z + a1.w)
             + (a2.x + a2.y + a2.z + a2.w) + (a3.x + a3.y + a3.z + a3.w);
    }

    // rho0 = K/sum(t): h(rho0) < K strictly -> monotone Newton from below
    float rho = (float)KSEL / sumt;

#pragma unroll 1
    for (int it = 0; it < NEWTON_ITERS; ++it) {
        float a = 0.f, q = 0.f;
#pragma unroll
        for (int e = 0; e < 4; ++e) {
            float w = fastrcp(fmaf(rho, t[e], 1.0f));
            a += w;
            q = fmaf(w, w, q);
        }
#pragma unroll
        for (int off = 32; off >= 1; off >>= 1) {
            a += __shfl_xor(a, off, 64);
            q += __shfl_xor(q, off, 64);
        }
        const int ph = it & 1;
        if (ln == 0) { lds[ph][wv * 2] = a; lds[ph][wv * 2 + 1] = q; }
        __syncthreads();               // one barrier/iter; ping-pong handles WAR
        a = 0.f; q = 0.f;
        const float4* p = (const float4*)lds[ph];
#pragma unroll
        for (int r = 0; r < 8; ++r) {  // layout a,q,a,q,... -> x,z are A; y,w are Q
            float4 f = p[r];
            a += f.x + f.z;
            q += f.y + f.w;
        }
        // h(rho) = N - A, h'(rho) = (A - Q)/rho
        rho += ((float)(KSEL - NCOLS) + a) * rho / (a - q);
    }

    // ---- write P: out[b,0,n] = mu*(1-w), out[b,1,n] = mu*w
    const float MU = 1.0f / (float)NCOLS;
    float4* o0 = (float4*)(out + (size_t)b * 2 * NCOLS);
    float4* o1 = (float4*)(out + (size_t)b * 2 * NCOLS + NCOLS);
    float r0[4], r1[4];
#pragma unroll
    for (int e = 0; e < 4; ++e) {
        float w  = fastrcp(fmaf(rho, t[e], 1.0f));
        float p1 = MU * w;
        r1[e] = p1;
        r0[e] = MU - p1;
    }
    o0[tid] = make_float4(r0[0], r0[1], r0[2], r0[3]);
    o1[tid] = make_float4(r1[0], r1[1], r1[2], r1[3]);
}

extern "C" void kernel_launch(void* const* d_in, const int* in_sizes, int n_in,
                              void* d_out, int out_size, void* d_ws, size_t ws_size,
                              hipStream_t stream) {
    const float* scores = (const float*)d_in[0];
    float* out = (float*)d_out;
    float* blkmax = (float*)d_ws;   // 1024 floats; every slot written, no init needed

    hipLaunchKernelGGL(kmax_kernel, dim3(KMAX_BLOCKS), dim3(256), 0, stream,
                       (const float4*)scores, blkmax);
    hipLaunchKernelGGL(sinkhorn_kernel, dim3(NROWS), dim3(1024), 0, stream,
                       scores, blkmax, out);
}

// Round 5
// 73.396 us; speedup vs baseline: 1.5328x; 1.0721x over previous
//
#include <hip/hip_runtime.h>

// Sinkhorn top-K collapsed to a per-row 1-D Newton solve. B=512, N=4096, K=256, eps=0.1.
// t[n] = exp((1-2*s[n]) * alpha), alpha = 1/(M*eps), M = global max of (s-anchor)^2.
// Solve h(rho) = sum_n rho*t/(rho*t+1) = K (concave, monotone; Newton from below,
// rho0 = K/sum(t)). P1 = mu*w, P0 = mu*(1-w), w = 1/(rho*t+1). Fixed point == the
// reference's machine-converged 200 Sinkhorn sweeps (absmax 9.5e-7, R1-R4).
//
// R5: solve kernel at 512 thr/block — 8 waves x 4 blocks/CU = 32 waves/CU (100%
// occupancy, same as R4) but half-width barriers and 2 independent float4
// loads/thread for ILP. (R4's 1024-thr blocks were neutral vs R2: 16-wave
// barriers ate the occupancy gain.) K1 now 512 blocks so K2's global-max gather
// is exactly 1 value/thread. Measured harness floor ~69 us (268 MB ws poison
// fill ~43 us + out poison + restore + gaps); kernel-side floor ~6-7 us.

#define NROWS 512
#define NCOLS 4096
#define KSEL 256
#define EPSREG 0.1f
#define NEWTON_ITERS 6

__device__ __forceinline__ float fastrcp(float x) {
#if __has_builtin(__builtin_amdgcn_rcpf)
    return __builtin_amdgcn_rcpf(x);
#else
    return 1.0f / x;
#endif
}

// ---- K1: per-block max of max(s^2,(s-1)^2); 512 blocks x 256 thr ----
__global__ __launch_bounds__(256) void kmax_kernel(const float4* __restrict__ s4,
                                                   float* __restrict__ blkmax) {
    const int tid = blockIdx.x * 256 + threadIdx.x;   // 131072 threads
    float m = 0.f;
#pragma unroll
    for (int j = 0; j < 4; ++j) {                     // 4*131072 = 524288 float4 = 2M floats
        float4 v = s4[tid + 131072 * j];
        m = fmaxf(m, fmaxf(v.x * v.x, (v.x - 1.f) * (v.x - 1.f)));
        m = fmaxf(m, fmaxf(v.y * v.y, (v.y - 1.f) * (v.y - 1.f)));
        m = fmaxf(m, fmaxf(v.z * v.z, (v.z - 1.f) * (v.z - 1.f)));
        m = fmaxf(m, fmaxf(v.w * v.w, (v.w - 1.f) * (v.w - 1.f)));
    }
#pragma unroll
    for (int off = 32; off >= 1; off >>= 1)
        m = fmaxf(m, __shfl_xor(m, off, 64));
    __shared__ float wmax[4];
    if ((threadIdx.x & 63) == 0) wmax[threadIdx.x >> 6] = m;
    __syncthreads();
    if (threadIdx.x == 0)
        blkmax[blockIdx.x] = fmaxf(fmaxf(wmax[0], wmax[1]), fmaxf(wmax[2], wmax[3]));
}

// ---- K2: per-row Newton solve + write P; 512 blocks x 512 thr (8 waves) ----
__global__ __launch_bounds__(512) void sinkhorn_kernel(const float* __restrict__ s,
                                                       const float* __restrict__ blkmax,
                                                       float* __restrict__ out) {
    const int b   = blockIdx.x;
    const int tid = threadIdx.x;
    const int wv  = tid >> 6;          // wave 0..7
    const int ln  = tid & 63;

    __shared__ __align__(16) float ldsm[8];
    __shared__ __align__(16) float ldss[8];
    __shared__ __align__(16) float lds[2][16];   // Newton ping-pong: 8 x {A,Q}

    // ---- row load (2 independent float4/thread), issued first
    const float4* srow = (const float4*)(s + (size_t)b * NCOLS);
    const float4 v0 = srow[tid];
    const float4 v1 = srow[tid + 512];

    // ---- global max from 512 block maxes (1/thread, coalesced, L2/L3-hot)
    float m = blkmax[tid];
#pragma unroll
    for (int off = 32; off >= 1; off >>= 1)
        m = fmaxf(m, __shfl_xor(m, off, 64));
    if (ln == 0) ldsm[wv] = m;
    __syncthreads();                   // barrier 1
    {
        const float4* p = (const float4*)ldsm;   // same-addr broadcast reads: free
        float4 a0 = p[0], a1 = p[1];
        m = fmaxf(fmaxf(fmaxf(a0.x, a0.y), fmaxf(a0.z, a0.w)),
                  fmaxf(fmaxf(a1.x, a1.y), fmaxf(a1.z, a1.w)));
    }
    const float alpha = 1.0f / (m * EPSREG);
    const float c2    = -2.0f * alpha;

    // ---- t = exp((1-2x)*alpha), 8 per thread, + sum(t)
    float t[8];
    const float xs[8] = {v0.x, v0.y, v0.z, v0.w, v1.x, v1.y, v1.z, v1.w};
    float sumt = 0.f;
#pragma unroll
    for (int e = 0; e < 8; ++e) {
        float tt = __expf(fmaf(xs[e], c2, alpha));
        t[e] = tt;
        sumt += tt;
    }
#pragma unroll
    for (int off = 32; off >= 1; off >>= 1)
        sumt += __shfl_xor(sumt, off, 64);
    if (ln == 0) ldss[wv] = sumt;
    __syncthreads();                   // barrier 2
    {
        const float4* p = (const float4*)ldss;
        float4 a0 = p[0], a1 = p[1];
        sumt = (a0.x + a0.y + a0.z + a0.w) + (a1.x + a1.y + a1.z + a1.w);
    }

    // rho0 = K/sum(t): h(rho0) < K strictly -> monotone Newton from below
    float rho = (float)KSEL / sumt;

#pragma unroll 1
    for (int it = 0; it < NEWTON_ITERS; ++it) {
        float a = 0.f, q = 0.f;
#pragma unroll
        for (int e = 0; e < 8; ++e) {
            float w = fastrcp(fmaf(rho, t[e], 1.0f));
            a += w;
            q = fmaf(w, w, q);
        }
#pragma unroll
        for (int off = 32; off >= 1; off >>= 1) {
            a += __shfl_xor(a, off, 64);
            q += __shfl_xor(q, off, 64);
        }
        const int ph = it & 1;
        if (ln == 0) { lds[ph][wv * 2] = a; lds[ph][wv * 2 + 1] = q; }
        __syncthreads();               // one barrier/iter; ping-pong handles WAR
        a = 0.f; q = 0.f;
        const float4* p = (const float4*)lds[ph];
#pragma unroll
        for (int r = 0; r < 4; ++r) {  // layout a,q,a,q,... -> x,z are A; y,w are Q
            float4 f = p[r];
            a += f.x + f.z;
            q += f.y + f.w;
        }
        // h(rho) = N - A, h'(rho) = (A - Q)/rho
        rho += ((float)(KSEL - NCOLS) + a) * rho / (a - q);
    }

    // ---- write P: out[b,0,n] = mu*(1-w), out[b,1,n] = mu*w
    const float MU = 1.0f / (float)NCOLS;
    float4* o0 = (float4*)(out + (size_t)b * 2 * NCOLS);
    float4* o1 = (float4*)(out + (size_t)b * 2 * NCOLS + NCOLS);
#pragma unroll
    for (int j = 0; j < 2; ++j) {
        float r0[4], r1[4];
#pragma unroll
        for (int e = 0; e < 4; ++e) {
            float w  = fastrcp(fmaf(rho, t[4 * j + e], 1.0f));
            float p1 = MU * w;
            r1[e] = p1;
            r0[e] = MU - p1;
        }
        o0[tid + 512 * j] = make_float4(r0[0], r0[1], r0[2], r0[3]);
        o1[tid + 512 * j] = make_float4(r1[0], r1[1], r1[2], r1[3]);
    }
}

extern "C" void kernel_launch(void* const* d_in, const int* in_sizes, int n_in,
                              void* d_out, int out_size, void* d_ws, size_t ws_size,
                              hipStream_t stream) {
    const float* scores = (const float*)d_in[0];
    float* out = (float*)d_out;
    float* blkmax = (float*)d_ws;   // 512 floats; every slot written, no init needed

    hipLaunchKernelGGL(kmax_kernel, dim3(512), dim3(256), 0, stream,
                       (const float4*)scores, blkmax);
    hipLaunchKernelGGL(sinkhorn_kernel, dim3(NROWS), dim3(512), 0, stream,
                       scores, blkmax, out);
}